// Round 1
// baseline (416.373 us; speedup 1.0000x reference)
//
#include <hip/hip_runtime.h>

// ---------------------------------------------------------------------------
// QLSTM: seq=256, batch=512, input=256, H=n_qubits=8.
// Kernel 1: Z[t][b][k][g] = x[t,b,:] @ W_g[k,0:256].T + b_g[k]   (parallel GEMM)
// Kernel 2: sequential scan, 8 lanes per batch element (lane = qubit k).
// ---------------------------------------------------------------------------

#define SEQ   256
#define BATCH 512
#define DIN   256
#define NROWS (SEQ * BATCH)      // 131072
#define DCOMB 264                // 256 + 8

// ------------------------------ kernel 1 -----------------------------------
// grid: NROWS/64 = 2048 blocks x 256 threads. 64-row x 256-K LDS tile (64 KB).
// cols c = k*4 + g  (c = 0..31); wave w handles cols w*8 .. w*8+7 (uniform ->
// weights become scalar s_loads).
__global__ __launch_bounds__(256, 2) void qlstm_gemm(
    const float* __restrict__ X,
    const float* __restrict__ Wf, const float* __restrict__ Wi,
    const float* __restrict__ Wu, const float* __restrict__ Wo,
    const float* __restrict__ bf, const float* __restrict__ bi,
    const float* __restrict__ bu, const float* __restrict__ bo,
    float* __restrict__ Z)
{
    __shared__ float xs[64 * 256];   // 64 KB, XOR-swizzled columns
    const int tid = threadIdx.x;
    const long rowbase = (long)blockIdx.x * 64;

    // stage 64 rows x 256 floats, coalesced float4 loads
    const float4* __restrict__ Xv = (const float4*)X + rowbase * 64;
    #pragma unroll
    for (int i = 0; i < 16; ++i) {
        int f = tid + (i << 8);          // float4 index in tile
        float4 v = Xv[f];
        int r = f >> 6, c = f & 63;      // row, float4-chunk
        *(float4*)&xs[(r << 8) + ((c ^ (r & 7)) << 2)] = v;
    }
    __syncthreads();

    const int r  = tid & 63;                                   // row in tile
    const int cg = __builtin_amdgcn_readfirstlane(tid >> 6);   // wave id 0..3
    const float* __restrict__ Ws[4] = {Wf, Wi, Wu, Wo};
    const float* __restrict__ Bs[4] = {bf, bi, bu, bo};
    const float* wr[8];
    float acc[8];
    #pragma unroll
    for (int i = 0; i < 8; ++i) {
        int g = i & 3, k = (cg << 1) + (i >> 2);   // col = cg*8+i = k*4+g
        wr[i]  = Ws[g] + k * DCOMB;
        acc[i] = Bs[g][k];
    }

    #pragma unroll 4
    for (int cc = 0; cc < 64; ++cc) {
        const float4 x4 = *(const float4*)&xs[(r << 8) + ((cc ^ (r & 7)) << 2)];
        #pragma unroll
        for (int i = 0; i < 8; ++i) {
            const float4 w4 = *(const float4*)(wr[i] + (cc << 2));  // s_load (uniform)
            acc[i] = fmaf(x4.x, w4.x, acc[i]);
            acc[i] = fmaf(x4.y, w4.y, acc[i]);
            acc[i] = fmaf(x4.z, w4.z, acc[i]);
            acc[i] = fmaf(x4.w, w4.w, acc[i]);
        }
    }

    float* zp = Z + (rowbase + r) * 32 + (cg << 3);
    *(float4*)zp       = make_float4(acc[0], acc[1], acc[2], acc[3]);
    *(float4*)(zp + 4) = make_float4(acc[4], acc[5], acc[6], acc[7]);
}

// ------------------------------ kernel 2 -----------------------------------
__device__ __forceinline__ float fast_sigmoid(float x) {
    return __builtin_amdgcn_rcpf(1.0f + __builtin_amdgcn_exp2f(-1.442695041f * x));
}
__device__ __forceinline__ float fast_tanh(float x) {
    return 1.0f - 2.0f * __builtin_amdgcn_rcpf(__builtin_amdgcn_exp2f(2.885390082f * x) + 1.0f);
}

// broadcast from lane ((lane & ~7) | J) within each 8-lane group (BitMode swizzle)
#define BCAST8(V, J) \
    __int_as_float(__builtin_amdgcn_ds_swizzle(__float_as_int(V), ((J) << 5) | 0x18))

// inclusive prefix product over 8-lane groups via DPP row_shr (Hillis-Steele)
#define PFXD(A, D) { \
    int s_ = __builtin_amdgcn_update_dpp(0, __float_as_int(A), 0x110 | (D), 0xF, 0xF, false); \
    float m_ = (kq >= (D)) ? __int_as_float(s_) : 1.0f; \
    (A) *= m_; }
#define PFX3(A) PFXD(A, 1) PFXD(A, 2) PFXD(A, 4)

// grid: 64 blocks x 64 threads = 4096 = 512 batches * 8 qubits
__global__ __launch_bounds__(64, 1) void qlstm_scan(
    const float* __restrict__ Z,
    const float* __restrict__ Wf, const float* __restrict__ Wi,
    const float* __restrict__ Wu, const float* __restrict__ Wo,
    const float* __restrict__ pf, const float* __restrict__ pi_,
    const float* __restrict__ pu, const float* __restrict__ po,
    float* __restrict__ out)
{
    const int tid = blockIdx.x * 64 + threadIdx.x;   // 0..4095 = b*8 + k
    const int kq  = tid & 7;                         // qubit index (== lane&7)
    const int woff = kq * DCOMB + DIN;               // recurrent weight offset

    float wh0[8], wh1[8], wh2[8], wh3[8];
    #pragma unroll
    for (int j = 0; j < 8; ++j) {
        wh0[j] = Wf[woff + j];
        wh1[j] = Wi[woff + j];
        wh2[j] = Wu[woff + j];
        wh3[j] = Wo[woff + j];
    }
    const float cth0 = __cosf(pf[kq]);
    const float cth1 = __cosf(pi_[kq]);
    const float cth2 = __cosf(pu[kq]);
    const float cth3 = __cosf(po[kq]);

    float hx = 0.0f, cx = 0.0f;
    const float4* __restrict__ Zv = (const float4*)Z;
    float4 z = Zv[tid];                              // t = 0 slice

    for (int t = 0; t < SEQ; ++t) {
        const int tn = (t < SEQ - 1) ? (t + 1) : (SEQ - 1);
        float4 zn = Zv[(tn << 12) + tid];            // prefetch next step

        float p0 = z.x, p1 = z.y, p2 = z.z, p3 = z.w;
        // pre += hx @ Wh.T : broadcast each hx_j within the 8-lane group
        #define STEPJ(J) { float hj = BCAST8(hx, J); \
            p0 = fmaf(hj, wh0[J], p0); p1 = fmaf(hj, wh1[J], p1); \
            p2 = fmaf(hj, wh2[J], p2); p3 = fmaf(hj, wh3[J], p3); }
        STEPJ(0) STEPJ(1) STEPJ(2) STEPJ(3) STEPJ(4) STEPJ(5) STEPJ(6) STEPJ(7)
        #undef STEPJ

        // qgate: a_k = cos(pre_k)*cos(theta_k); gate = cumprod_{j<=k} a_j
        float a0 = __cosf(p0) * cth0;
        float a1 = __cosf(p1) * cth1;
        float a2 = __cosf(p2) * cth2;
        float a3 = __cosf(p3) * cth3;
        PFX3(a0) PFX3(a1) PFX3(a2) PFX3(a3)

        float fg = fast_sigmoid(a0);
        float ig = fast_sigmoid(a1);
        float ug = fast_tanh(a2);
        float og = fast_sigmoid(a3);

        cx = fmaf(fg, cx, ig * ug);
        hx = og * fast_tanh(cx);

        out[(t << 12) + tid] = hx;                   // stacked[t][b][k]
        z = zn;
    }
    out[NROWS * 8 + tid]        = hx;                // final hx (512,8)
    out[NROWS * 8 + 4096 + tid] = cx;                // final cx (512,8)
}

// ---------------------------------------------------------------------------
extern "C" void kernel_launch(void* const* d_in, const int* in_sizes, int n_in,
                              void* d_out, int out_size, void* d_ws, size_t ws_size,
                              hipStream_t stream) {
    const float* X   = (const float*)d_in[0];
    const float* Wf  = (const float*)d_in[1];
    const float* bf  = (const float*)d_in[2];
    const float* Wi  = (const float*)d_in[3];
    const float* bi  = (const float*)d_in[4];
    const float* Wu  = (const float*)d_in[5];
    const float* bu  = (const float*)d_in[6];
    const float* Wo  = (const float*)d_in[7];
    const float* bo  = (const float*)d_in[8];
    const float* pf  = (const float*)d_in[9];
    const float* pi_ = (const float*)d_in[10];
    const float* pu  = (const float*)d_in[11];
    const float* po  = (const float*)d_in[12];
    float* out = (float*)d_out;
    float* Z   = (float*)d_ws;   // 131072 * 32 * 4 B = 16.8 MB scratch

    qlstm_gemm<<<NROWS / 64, 256, 0, stream>>>(X, Wf, Wi, Wu, Wo, bf, bi, bu, bo, Z);
    qlstm_scan<<<64, 64, 0, stream>>>(Z, Wf, Wi, Wu, Wo, pf, pi_, pu, po, out);
}

// Round 2
// 301.960 us; speedup vs baseline: 1.3789x; 1.3789x over previous
//
#include <hip/hip_runtime.h>
#include <hip/hip_bf16.h>

// ---------------------------------------------------------------------------
// QLSTM: seq=256, batch=512, input=256, H=n_qubits=8.
// Kernel 1 (MFMA): Z[row][c] = x[row,:] @ W_g[kq,:256].T + b_g[kq],
//                  row=(t,b), c = kq*4+g, via 16x16x32 bf16 MFMA,
//                  weights held as hi+lo bf16 fragments (fp32-exact weights).
// Kernel 2: sequential scan, 8 lanes per batch element, 8-deep Z prefetch ring.
// ---------------------------------------------------------------------------

#define SEQ   256
#define BATCH 512
#define DIN   256
#define NROWS (SEQ * BATCH)      // 131072
#define DCOMB 264                // 256 + 8

typedef __attribute__((ext_vector_type(8))) short short8;
typedef __attribute__((ext_vector_type(4))) float f32x4;

__device__ __forceinline__ short f2bf(float f) {
    union { __hip_bfloat16 h; short s; } u;
    u.h = __float2bfloat16(f);
    return u.s;
}
__device__ __forceinline__ float bf2f(short s) {
    union { short s; __hip_bfloat16 h; } u;
    u.s = s;
    return __bfloat162float(u.h);
}

// ------------------------------ kernel 1 -----------------------------------
// grid: 2048 blocks x 256 threads; each wave = one 16-row M-tile x 32 cols.
// No LDS. A: direct global loads (each lane: 8 contiguous k of its row).
// B: weights packed once per wave into hi+lo bf16 fragments (128 VGPRs).
// Verified layouts (m89/m120): A[m=lane&15][k=(lane>>4)*8+j],
// B[n=lane&15][k=(lane>>4)*8+j], D col=lane&15, row=(lane>>4)*4+reg.
__global__ __launch_bounds__(256) void qlstm_gemm(
    const float* __restrict__ X,
    const float* __restrict__ Wf, const float* __restrict__ Wi,
    const float* __restrict__ Wu, const float* __restrict__ Wo,
    const float* __restrict__ bfv, const float* __restrict__ biv,
    const float* __restrict__ buv, const float* __restrict__ bov,
    float* __restrict__ Z)
{
    const int l   = threadIdx.x & 63;
    const int wid = threadIdx.x >> 6;
    const int lm  = l & 15;          // row-in-tile (A/D) / col-in-tile (B)
    const int lk  = l >> 4;          // k-quad
    const int row0 = blockIdx.x * 64 + wid * 16;

    const float* Wg[4] = {Wf, Wi, Wu, Wo};
    const float* Bg[4] = {bfv, biv, buv, bov};

    // ---- build B fragments: col c = nt*16 + lm = kq*4 + g ----
    short8 Bhi[2][8], Blo[2][8];
    #pragma unroll
    for (int nt = 0; nt < 2; ++nt) {
        const int c  = nt * 16 + lm;
        const float* wrow = Wg[c & 3] + (c >> 2) * DCOMB;
        #pragma unroll
        for (int ks = 0; ks < 8; ++ks) {
            const float* p = wrow + ks * 32 + lk * 8;
            const float4 w0 = *(const float4*)p;
            const float4 w1 = *(const float4*)(p + 4);
            const float wv[8] = {w0.x, w0.y, w0.z, w0.w, w1.x, w1.y, w1.z, w1.w};
            #pragma unroll
            for (int j = 0; j < 8; ++j) {
                const short hi = f2bf(wv[j]);
                Bhi[nt][ks][j] = hi;
                Blo[nt][ks][j] = f2bf(wv[j] - bf2f(hi));
            }
        }
    }

    // ---- acc init = bias (per col, every row) ----
    f32x4 acc[2];
    #pragma unroll
    for (int nt = 0; nt < 2; ++nt) {
        const int c = nt * 16 + lm;
        const float b = Bg[c & 3][c >> 2];
        acc[nt] = (f32x4){b, b, b, b};
    }

    // ---- K loop: 8 steps of K=32, X read exactly once, coalesced ----
    const float* xbase = X + (long)(row0 + lm) * DIN + lk * 8;
    #pragma unroll
    for (int ks = 0; ks < 8; ++ks) {
        const float4 x0 = *(const float4*)(xbase + ks * 32);
        const float4 x1 = *(const float4*)(xbase + ks * 32 + 4);
        const float xv[8] = {x0.x, x0.y, x0.z, x0.w, x1.x, x1.y, x1.z, x1.w};
        short8 a;
        #pragma unroll
        for (int j = 0; j < 8; ++j) a[j] = f2bf(xv[j]);
        acc[0] = __builtin_amdgcn_mfma_f32_16x16x32_bf16(a, Bhi[0][ks], acc[0], 0, 0, 0);
        acc[0] = __builtin_amdgcn_mfma_f32_16x16x32_bf16(a, Blo[0][ks], acc[0], 0, 0, 0);
        acc[1] = __builtin_amdgcn_mfma_f32_16x16x32_bf16(a, Bhi[1][ks], acc[1], 0, 0, 0);
        acc[1] = __builtin_amdgcn_mfma_f32_16x16x32_bf16(a, Blo[1][ks], acc[1], 0, 0, 0);
    }

    // ---- store: D row = row0 + lk*4 + r, col = nt*16 + lm ----
    #pragma unroll
    for (int nt = 0; nt < 2; ++nt)
        #pragma unroll
        for (int r = 0; r < 4; ++r)
            Z[(long)(row0 + lk * 4 + r) * 32 + nt * 16 + lm] = acc[nt][r];
}

// ------------------------------ kernel 2 -----------------------------------
__device__ __forceinline__ float fast_sigmoid(float x) {
    return __builtin_amdgcn_rcpf(1.0f + __builtin_amdgcn_exp2f(-1.442695041f * x));
}
__device__ __forceinline__ float fast_tanh(float x) {
    return 1.0f - 2.0f * __builtin_amdgcn_rcpf(__builtin_amdgcn_exp2f(2.885390082f * x) + 1.0f);
}

// broadcast from lane ((lane & ~7) | J) within each 8-lane group (BitMode swizzle)
#define BCAST8(V, J) \
    __int_as_float(__builtin_amdgcn_ds_swizzle(__float_as_int(V), ((J) << 5) | 0x18))

// inclusive prefix product over 8-lane groups via DPP row_shr (Hillis-Steele)
#define PFXD(A, D) { \
    int s_ = __builtin_amdgcn_update_dpp(0, __float_as_int(A), 0x110 | (D), 0xF, 0xF, false); \
    float m_ = (kq >= (D)) ? __int_as_float(s_) : 1.0f; \
    (A) *= m_; }
#define PFX3(A) PFXD(A, 1) PFXD(A, 2) PFXD(A, 4)

#define PF 8   // prefetch ring depth

// grid: 64 blocks x 64 threads = 4096 = 512 batches * 8 qubits
__global__ __launch_bounds__(64, 1) void qlstm_scan(
    const float* __restrict__ Z,
    const float* __restrict__ Wf, const float* __restrict__ Wi,
    const float* __restrict__ Wu, const float* __restrict__ Wo,
    const float* __restrict__ pf, const float* __restrict__ pi_,
    const float* __restrict__ pu, const float* __restrict__ po,
    float* __restrict__ out)
{
    const int tid = blockIdx.x * 64 + threadIdx.x;   // 0..4095 = b*8 + k
    const int kq  = tid & 7;                         // qubit index (== lane&7)
    const int woff = kq * DCOMB + DIN;               // recurrent weight offset

    float wh0[8], wh1[8], wh2[8], wh3[8];
    #pragma unroll
    for (int j = 0; j < 8; ++j) {
        wh0[j] = Wf[woff + j];
        wh1[j] = Wi[woff + j];
        wh2[j] = Wu[woff + j];
        wh3[j] = Wo[woff + j];
    }
    const float cth0 = __cosf(pf[kq]);
    const float cth1 = __cosf(pi_[kq]);
    const float cth2 = __cosf(pu[kq]);
    const float cth3 = __cosf(po[kq]);

    float hx = 0.0f, cx = 0.0f;
    const float4* __restrict__ Zv = (const float4*)Z;

    float4 ring[PF];
    #pragma unroll
    for (int i = 0; i < PF; ++i) ring[i] = Zv[(i << 12) + tid];

    for (int t0 = 0; t0 < SEQ; t0 += PF) {
        #pragma unroll
        for (int u = 0; u < PF; ++u) {
            const int t = t0 + u;
            const float4 z = ring[u];
            int tn = t + PF; if (tn > SEQ - 1) tn = SEQ - 1;
            ring[u] = Zv[(tn << 12) + tid];          // deep prefetch

            // gather all 8 hx values of the group (independent swizzles)
            const float h0 = BCAST8(hx, 0), h1 = BCAST8(hx, 1);
            const float h2 = BCAST8(hx, 2), h3 = BCAST8(hx, 3);
            const float h4 = BCAST8(hx, 4), h5 = BCAST8(hx, 5);
            const float h6 = BCAST8(hx, 6), h7 = BCAST8(hx, 7);

            // pre += hx @ Wh.T, two 4-deep chains per gate
            #define GATE(P, W) float P; { \
                float pa = fmaf(h0, W[0], z_); pa = fmaf(h1, W[1], pa); \
                pa = fmaf(h2, W[2], pa); pa = fmaf(h3, W[3], pa); \
                float pb = h4 * W[4]; pb = fmaf(h5, W[5], pb); \
                pb = fmaf(h6, W[6], pb); pb = fmaf(h7, W[7], pb); \
                P = pa + pb; }
            float z_;
            z_ = z.x; GATE(p0, wh0)
            z_ = z.y; GATE(p1, wh1)
            z_ = z.z; GATE(p2, wh2)
            z_ = z.w; GATE(p3, wh3)
            #undef GATE

            // qgate: a_k = cos(pre_k)*cos(theta_k); gate = cumprod_{j<=k} a_j
            float a0 = __cosf(p0) * cth0;
            float a1 = __cosf(p1) * cth1;
            float a2 = __cosf(p2) * cth2;
            float a3 = __cosf(p3) * cth3;
            PFX3(a0) PFX3(a1) PFX3(a2) PFX3(a3)

            const float fg = fast_sigmoid(a0);
            const float ig = fast_sigmoid(a1);
            const float ug = fast_tanh(a2);
            const float og = fast_sigmoid(a3);

            cx = fmaf(fg, cx, ig * ug);
            hx = og * fast_tanh(cx);

            out[(t << 12) + tid] = hx;               // stacked[t][b][k]
        }
    }
    out[NROWS * 8 + tid]        = hx;                // final hx (512,8)
    out[NROWS * 8 + 4096 + tid] = cx;                // final cx (512,8)
}

// ---------------------------------------------------------------------------
extern "C" void kernel_launch(void* const* d_in, const int* in_sizes, int n_in,
                              void* d_out, int out_size, void* d_ws, size_t ws_size,
                              hipStream_t stream) {
    const float* X   = (const float*)d_in[0];
    const float* Wf  = (const float*)d_in[1];
    const float* bfv = (const float*)d_in[2];
    const float* Wi  = (const float*)d_in[3];
    const float* biv = (const float*)d_in[4];
    const float* Wu  = (const float*)d_in[5];
    const float* buv = (const float*)d_in[6];
    const float* Wo  = (const float*)d_in[7];
    const float* bov = (const float*)d_in[8];
    const float* pf  = (const float*)d_in[9];
    const float* pi_ = (const float*)d_in[10];
    const float* pu  = (const float*)d_in[11];
    const float* po  = (const float*)d_in[12];
    float* out = (float*)d_out;
    float* Z   = (float*)d_ws;   // 131072 * 32 * 4 B = 16.8 MB scratch

    qlstm_gemm<<<NROWS / 64, 256, 0, stream>>>(X, Wf, Wi, Wu, Wo, bfv, biv, buv, bov, Z);
    qlstm_scan<<<64, 64, 0, stream>>>(Z, Wf, Wi, Wu, Wo, pf, pi_, pu, po, out);
}

// Round 4
// 287.408 us; speedup vs baseline: 1.4487x; 1.0506x over previous
//
#include <hip/hip_runtime.h>
#include <hip/hip_bf16.h>

// ---------------------------------------------------------------------------
// QLSTM: seq=256, batch=512, input=256, H=n_qubits=8.
// Kernel 0 (pack): build bf16 hi/lo B-fragments + bias table in d_ws (1 wave).
// Kernel 1 (MFMA): Z[row][c] = x[row,:] @ W_g[kq,:256].T + b_g[kq]  (16x16x32).
// Kernel 2 (scan): 16 lanes/batch (qubits replicated in high 8 lanes),
//                  hx@Wh via DPP row_ror rotations — zero LDS ops in the loop.
// ---------------------------------------------------------------------------

#define SEQ   256
#define BATCH 512
#define DIN   256
#define NROWS (SEQ * BATCH)      // 131072
#define DCOMB 264                // 256 + 8
#define ZBYTES (NROWS * 32 * 4)  // 16.8 MB

typedef __attribute__((ext_vector_type(8))) short short8;
typedef __attribute__((ext_vector_type(4))) float f32x4;
typedef __attribute__((ext_vector_type(2))) float f32x2;

__device__ __forceinline__ short f2bf(float f) {
    union { __hip_bfloat16 h; short s; } u;
    u.h = __float2bfloat16(f);
    return u.s;
}
__device__ __forceinline__ float bf2f(short s) {
    union { short s; __hip_bfloat16 h; } u;
    u.s = s;
    return __bfloat162float(u.h);
}

// ------------------------------ kernel 0: pack -----------------------------
// One wave. Lane l=(lk*16+lm) builds its B fragments for both 16-col tiles:
// col c = nt*16+lm = kq*4+g ; k-index = ks*32 + lk*8 + j.
// Layout: wsB[((nt*8+ks)*2 + hiLo)*64 + l]  (short8 = 16 B each), 32 KB total.
__global__ __launch_bounds__(64) void qlstm_pack(
    const float* __restrict__ Wf, const float* __restrict__ Wi,
    const float* __restrict__ Wu, const float* __restrict__ Wo,
    const float* __restrict__ bfv, const float* __restrict__ biv,
    const float* __restrict__ buv, const float* __restrict__ bov,
    short8* __restrict__ wsB, float* __restrict__ wsBias)
{
    const int l  = threadIdx.x;
    const int lm = l & 15, lk = l >> 4;
    const float* Wg[4] = {Wf, Wi, Wu, Wo};
    const float* Bg[4] = {bfv, biv, buv, bov};

    #pragma unroll
    for (int nt = 0; nt < 2; ++nt) {
        const int c = nt * 16 + lm;
        const float* wrow = Wg[c & 3] + (c >> 2) * DCOMB;
        #pragma unroll
        for (int ks = 0; ks < 8; ++ks) {
            const float* p = wrow + ks * 32 + lk * 8;
            const float4 w0 = *(const float4*)p;
            const float4 w1 = *(const float4*)(p + 4);
            const float wv[8] = {w0.x, w0.y, w0.z, w0.w, w1.x, w1.y, w1.z, w1.w};
            short8 hi8, lo8;
            #pragma unroll
            for (int j = 0; j < 8; ++j) {
                const short hi = f2bf(wv[j]);
                hi8[j] = hi;
                lo8[j] = f2bf(wv[j] - bf2f(hi));
            }
            wsB[((nt * 8 + ks) * 2 + 0) * 64 + l] = hi8;
            wsB[((nt * 8 + ks) * 2 + 1) * 64 + l] = lo8;
        }
    }
    if (l < 32) wsBias[l] = Bg[l & 3][l >> 2];   // bias[c], c = kq*4+g
}

// ------------------------------ kernel 1: gemm -----------------------------
__device__ __forceinline__ short8 pack8(float4 a, float4 b) {
    union { short8 s8; int i[4]; } u;
    union { __hip_bfloat162 h; int i; } v;
    v.h = __float22bfloat162_rn(make_float2(a.x, a.y)); u.i[0] = v.i;
    v.h = __float22bfloat162_rn(make_float2(a.z, a.w)); u.i[1] = v.i;
    v.h = __float22bfloat162_rn(make_float2(b.x, b.y)); u.i[2] = v.i;
    v.h = __float22bfloat162_rn(make_float2(b.z, b.w)); u.i[3] = v.i;
    return u.s8;
}

// grid: 2048 blocks x 256 threads; each wave = one 16-row M-tile x 32 cols.
// A: direct coalesced global loads; B: prepacked fragments from L2.
__global__ __launch_bounds__(256) void qlstm_gemm(
    const float* __restrict__ X,
    const short8* __restrict__ wsB, const float* __restrict__ wsBias,
    float* __restrict__ Z)
{
    const int l   = threadIdx.x & 63;
    const int wid = threadIdx.x >> 6;
    const int lm  = l & 15;          // row-in-tile (A/D) / col-in-tile (B)
    const int lk  = l >> 4;          // k-quad
    const int row0 = blockIdx.x * 64 + wid * 16;

    f32x4 acc[2];
    #pragma unroll
    for (int nt = 0; nt < 2; ++nt) {
        const float b = wsBias[nt * 16 + lm];
        acc[nt] = (f32x4){b, b, b, b};
    }

    const float* xbase = X + (long)(row0 + lm) * DIN + lk * 8;
    #pragma unroll 2
    for (int ks = 0; ks < 8; ++ks) {
        const float4 x0 = *(const float4*)(xbase + ks * 32);
        const float4 x1 = *(const float4*)(xbase + ks * 32 + 4);
        const short8 bh0 = wsB[((0 * 8 + ks) * 2 + 0) * 64 + l];
        const short8 bl0 = wsB[((0 * 8 + ks) * 2 + 1) * 64 + l];
        const short8 bh1 = wsB[((1 * 8 + ks) * 2 + 0) * 64 + l];
        const short8 bl1 = wsB[((1 * 8 + ks) * 2 + 1) * 64 + l];
        const short8 a = pack8(x0, x1);
        acc[0] = __builtin_amdgcn_mfma_f32_16x16x32_bf16(a, bh0, acc[0], 0, 0, 0);
        acc[0] = __builtin_amdgcn_mfma_f32_16x16x32_bf16(a, bl0, acc[0], 0, 0, 0);
        acc[1] = __builtin_amdgcn_mfma_f32_16x16x32_bf16(a, bh1, acc[1], 0, 0, 0);
        acc[1] = __builtin_amdgcn_mfma_f32_16x16x32_bf16(a, bl1, acc[1], 0, 0, 0);
    }

    // D row = row0 + lk*4 + r, col = nt*16 + lm
    #pragma unroll
    for (int nt = 0; nt < 2; ++nt)
        #pragma unroll
        for (int r = 0; r < 4; ++r)
            Z[(long)(row0 + lk * 4 + r) * 32 + nt * 16 + lm] = acc[nt][r];
}

// ------------------------------ kernel 2: scan -----------------------------
__device__ __forceinline__ float fast_sigmoid(float x) {
    return __builtin_amdgcn_rcpf(1.0f + __builtin_amdgcn_exp2f(-1.442695041f * x));
}
__device__ __forceinline__ float fast_tanh(float x) {
    return 1.0f - 2.0f * __builtin_amdgcn_rcpf(__builtin_amdgcn_exp2f(2.885390082f * x) + 1.0f);
}

// DPP helpers (16-lane row ops; each row = one batch, qubits replicated x2).
// VERIFIED convention (R1/R2 prefix + LLVM scan idiom): row_shr:d ->
// dst[i] = src[i-d] (invalid src -> old). row_ror:s is the same direction
// with wraparound: dst[i] = src[(i-s) mod 16].
#define DPP_ROR(V, S) \
    __int_as_float(__builtin_amdgcn_update_dpp(__float_as_int(V), __float_as_int(V), 0x120 | (S), 0xF, 0xF, false))
#define DPP_SHR_ONE(V, D) \
    __int_as_float(__builtin_amdgcn_update_dpp(one_i, __float_as_int(V), 0x110 | (D), 0xF, 0xF, false))
// replicate low half -> high half: row_shr:8, old=V keeps lanes 0-7 intact
#define DPP_REPL8(V) \
    __int_as_float(__builtin_amdgcn_update_dpp(__float_as_int(V), __float_as_int(V), 0x118, 0xF, 0xF, false))

#define PFX3(A) { A *= DPP_SHR_ONE(A, 1); A *= DPP_SHR_ONE(A, 2); A *= DPP_SHR_ONE(A, 4); }

#define PF 8   // prefetch ring depth

// grid: 128 blocks x 64 threads = 8192 = 512 batches * 16 lanes
__global__ __launch_bounds__(64, 1) void qlstm_scan(
    const float* __restrict__ Z,
    const float* __restrict__ Wf, const float* __restrict__ Wi,
    const float* __restrict__ Wu, const float* __restrict__ Wo,
    const float* __restrict__ pf, const float* __restrict__ pi_,
    const float* __restrict__ pu, const float* __restrict__ po,
    float* __restrict__ out)
{
    const int tid = blockIdx.x * 64 + threadIdx.x;   // 0..8191
    const int q   = threadIdx.x & 15;                // lane-in-batch 0..15
    const int kq  = q & 7;                           // qubit index
    const int b   = tid >> 4;                        // batch 0..511
    const int oidx = b * 8 + kq;                     // element index in a slice
    const int woff = kq * DCOMB + DIN;

    // pre-rotated recurrent weights: at rotation s, lane holds hx_{(kq-s)&7}
    f32x2 w01[8], w23[8];
    #pragma unroll
    for (int s = 0; s < 8; ++s) {
        const int j = (kq - s) & 7;
        w01[s] = (f32x2){Wf[woff + j], Wi[woff + j]};
        w23[s] = (f32x2){Wu[woff + j], Wo[woff + j]};
    }
    const float cth0 = __cosf(pf[kq]);
    const float cth1 = __cosf(pi_[kq]);
    const float cth2 = __cosf(pu[kq]);
    const float cth3 = __cosf(po[kq]);
    const int one_i = __float_as_int(1.0f);

    float hx = 0.0f, cx = 0.0f;
    const float4* __restrict__ Zv = (const float4*)Z;
    float* __restrict__ outp = out + oidx;

    float4 ring[PF];
    #pragma unroll
    for (int i = 0; i < PF; ++i) ring[i] = Zv[(i << 12) + oidx];

    for (int t0 = 0; t0 < SEQ; t0 += PF) {
        #pragma unroll
        for (int u = 0; u < PF; ++u) {
            const int t = t0 + u;
            const float4 z = ring[u];
            int tn = t + PF; if (tn > SEQ - 1) tn = SEQ - 1;
            ring[u] = Zv[(tn << 12) + oidx];         // deep prefetch

            // 7 independent DPP rotations of hx (mod-8 exact via replication)
            float h0 = hx;
            float h1 = DPP_ROR(hx, 1), h2 = DPP_ROR(hx, 2);
            float h3 = DPP_ROR(hx, 3), h4 = DPP_ROR(hx, 4);
            float h5 = DPP_ROR(hx, 5), h6 = DPP_ROR(hx, 6);
            float h7 = DPP_ROR(hx, 7);

            // pre = z + hx @ Wh.T, packed f32x2 per gate-pair, two 4-chains
            f32x2 pa01 = (f32x2){z.x, z.y} + (f32x2){h0, h0} * w01[0];
            f32x2 pa23 = (f32x2){z.z, z.w} + (f32x2){h0, h0} * w23[0];
            f32x2 pb01 = (f32x2){h4, h4} * w01[4];
            f32x2 pb23 = (f32x2){h4, h4} * w23[4];
            pa01 += (f32x2){h1, h1} * w01[1]; pa23 += (f32x2){h1, h1} * w23[1];
            pb01 += (f32x2){h5, h5} * w01[5]; pb23 += (f32x2){h5, h5} * w23[5];
            pa01 += (f32x2){h2, h2} * w01[2]; pa23 += (f32x2){h2, h2} * w23[2];
            pb01 += (f32x2){h6, h6} * w01[6]; pb23 += (f32x2){h6, h6} * w23[6];
            pa01 += (f32x2){h3, h3} * w01[3]; pa23 += (f32x2){h3, h3} * w23[3];
            pb01 += (f32x2){h7, h7} * w01[7]; pb23 += (f32x2){h7, h7} * w23[7];
            const f32x2 p01 = pa01 + pb01;
            const f32x2 p23 = pa23 + pb23;

            // qgate: a_k = cos(pre_k)*cos(theta_k); gate = cumprod_{j<=k}
            // (lanes 8-15 compute garbage prefixes for kq<4 — discarded)
            float a0 = __cosf(p01.x) * cth0;
            float a1 = __cosf(p01.y) * cth1;
            float a2 = __cosf(p23.x) * cth2;
            float a3 = __cosf(p23.y) * cth3;
            PFX3(a0) PFX3(a1) PFX3(a2) PFX3(a3)

            const float fg = fast_sigmoid(a0);
            const float ig = fast_sigmoid(a1);
            const float ug = fast_tanh(a2);
            const float og = fast_sigmoid(a3);

            cx = fmaf(fg, cx, ig * ug);              // cx valid in lanes 0-7 only
            hx = og * fast_tanh(cx);
            hx = DPP_REPL8(hx);                      // lanes 8-15 <- lanes 0-7

            outp[t << 12] = hx;                      // dup lanes write same bits
        }
    }
    if (q < 8) {
        out[NROWS * 8 + oidx]        = hx;           // final hx (512,8)
        out[NROWS * 8 + 4096 + oidx] = cx;           // final cx (512,8)
    }
}

// ---------------------------------------------------------------------------
extern "C" void kernel_launch(void* const* d_in, const int* in_sizes, int n_in,
                              void* d_out, int out_size, void* d_ws, size_t ws_size,
                              hipStream_t stream) {
    const float* X   = (const float*)d_in[0];
    const float* Wf  = (const float*)d_in[1];
    const float* bfv = (const float*)d_in[2];
    const float* Wi  = (const float*)d_in[3];
    const float* biv = (const float*)d_in[4];
    const float* Wu  = (const float*)d_in[5];
    const float* buv = (const float*)d_in[6];
    const float* Wo  = (const float*)d_in[7];
    const float* bov = (const float*)d_in[8];
    const float* pf  = (const float*)d_in[9];
    const float* pi_ = (const float*)d_in[10];
    const float* pu  = (const float*)d_in[11];
    const float* po  = (const float*)d_in[12];
    float* out = (float*)d_out;

    char* ws = (char*)d_ws;
    float*  Z      = (float*)ws;                       // 16.8 MB
    short8* wsB    = (short8*)(ws + ZBYTES);           // 32 KB fragments
    float*  wsBias = (float*)(ws + ZBYTES + 32768);    // 128 B

    qlstm_pack<<<1, 64, 0, stream>>>(Wf, Wi, Wu, Wo, bfv, biv, buv, bov, wsB, wsBias);
    qlstm_gemm<<<NROWS / 64, 256, 0, stream>>>(X, wsB, wsBias, Z);
    qlstm_scan<<<128, 64, 0, stream>>>(Z, Wf, Wi, Wu, Wo, pf, pi_, pu, po, out);
}

// Round 5
// 282.743 us; speedup vs baseline: 1.4726x; 1.0165x over previous
//
#include <hip/hip_runtime.h>
#include <hip/hip_bf16.h>

// ---------------------------------------------------------------------------
// QLSTM: seq=256, batch=512, input=256, H=n_qubits=8.
// Kernel 1 (MFMA, persistent): Z[row][c] = x[row,:]@W_g[kq,:256].T + b_g[kq],
//   c = kq*4+g. 512 blocks x 256 thr; each wave builds bf16 hi/lo B-fragments
//   once in registers, then processes 4 chunks of 16 rows (X read once).
// Kernel 2 (scan): 16 lanes/batch (qubits replicated in high 8 lanes),
//   hx@Wh via DPP row_ror rotations — zero LDS ops in the loop.
// ---------------------------------------------------------------------------

#define SEQ   256
#define BATCH 512
#define DIN   256
#define NROWS (SEQ * BATCH)      // 131072
#define DCOMB 264                // 256 + 8
#define MCHUNKS 4                // 64-row chunks per block (512 blocks)

typedef __attribute__((ext_vector_type(8))) short short8;
typedef __attribute__((ext_vector_type(4))) float f32x4;
typedef __attribute__((ext_vector_type(2))) float f32x2;

__device__ __forceinline__ short f2bf(float f) {
    union { __hip_bfloat16 h; short s; } u;
    u.h = __float2bfloat16(f);
    return u.s;
}
__device__ __forceinline__ float bf2f(short s) {
    union { short s; __hip_bfloat16 h; } u;
    u.s = s;
    return __bfloat162float(u.h);
}

// ------------------------------ kernel 1: gemm -----------------------------
__device__ __forceinline__ short8 pack8(float4 a, float4 b) {
    union { short8 s8; int i[4]; } u;
    union { __hip_bfloat162 h; int i; } v;
    v.h = __float22bfloat162_rn(make_float2(a.x, a.y)); u.i[0] = v.i;
    v.h = __float22bfloat162_rn(make_float2(a.z, a.w)); u.i[1] = v.i;
    v.h = __float22bfloat162_rn(make_float2(b.x, b.y)); u.i[2] = v.i;
    v.h = __float22bfloat162_rn(make_float2(b.z, b.w)); u.i[3] = v.i;
    return u.s8;
}

// Verified layouts (R1..R4 passing): A[m=lane&15][k=(lane>>4)*8+j],
// B[n=lane&15][k=(lane>>4)*8+j], D col=lane&15, row=(lane>>4)*4+reg.
__global__ __launch_bounds__(256) void qlstm_gemm(
    const float* __restrict__ X,
    const float* __restrict__ Wf, const float* __restrict__ Wi,
    const float* __restrict__ Wu, const float* __restrict__ Wo,
    const float* __restrict__ bfv, const float* __restrict__ biv,
    const float* __restrict__ buv, const float* __restrict__ bov,
    float* __restrict__ Z)
{
    const int l   = threadIdx.x & 63;
    const int wid = threadIdx.x >> 6;
    const int lm  = l & 15;          // row-in-tile (A/D) / col-in-tile (B)
    const int lk  = l >> 4;          // k-quad

    const float* Wg[4] = {Wf, Wi, Wu, Wo};
    const float* Bg[4] = {bfv, biv, buv, bov};

    // ---- build B fragments ONCE per wave (held in registers) ----
    short8 Bhi[2][8], Blo[2][8];
    float bias[2];
    #pragma unroll
    for (int nt = 0; nt < 2; ++nt) {
        const int c = nt * 16 + lm;                  // col = kq*4 + g
        const float* wrow = Wg[c & 3] + (c >> 2) * DCOMB;
        bias[nt] = Bg[c & 3][c >> 2];
        #pragma unroll
        for (int ks = 0; ks < 8; ++ks) {
            const float* p = wrow + ks * 32 + lk * 8;
            const float4 w0 = *(const float4*)p;
            const float4 w1 = *(const float4*)(p + 4);
            const float wv[8] = {w0.x, w0.y, w0.z, w0.w, w1.x, w1.y, w1.z, w1.w};
            #pragma unroll
            for (int j = 0; j < 8; ++j) {
                const short hi = f2bf(wv[j]);
                Bhi[nt][ks][j] = hi;
                Blo[nt][ks][j] = f2bf(wv[j] - bf2f(hi));
            }
        }
    }

    // ---- 4 chunks of 16 rows per wave; X read exactly once, coalesced ----
    #pragma unroll
    for (int ch = 0; ch < MCHUNKS; ++ch) {
        const int row0 = (blockIdx.x * MCHUNKS + ch) * 64 + wid * 16;
        const float* xbase = X + (long)(row0 + lm) * DIN + lk * 8;

        float4 xv[16];                               // all 16 loads in flight
        #pragma unroll
        for (int i = 0; i < 16; ++i)
            xv[i] = *(const float4*)(xbase + (i >> 1) * 32 + (i & 1) * 4);

        f32x4 acc0 = (f32x4){bias[0], bias[0], bias[0], bias[0]};
        f32x4 acc1 = (f32x4){bias[1], bias[1], bias[1], bias[1]};
        #pragma unroll
        for (int ks = 0; ks < 8; ++ks) {
            const short8 a = pack8(xv[2 * ks], xv[2 * ks + 1]);
            acc0 = __builtin_amdgcn_mfma_f32_16x16x32_bf16(a, Bhi[0][ks], acc0, 0, 0, 0);
            acc0 = __builtin_amdgcn_mfma_f32_16x16x32_bf16(a, Blo[0][ks], acc0, 0, 0, 0);
            acc1 = __builtin_amdgcn_mfma_f32_16x16x32_bf16(a, Bhi[1][ks], acc1, 0, 0, 0);
            acc1 = __builtin_amdgcn_mfma_f32_16x16x32_bf16(a, Blo[1][ks], acc1, 0, 0, 0);
        }

        // D row = row0 + lk*4 + r, col = nt*16 + lm
        #pragma unroll
        for (int r = 0; r < 4; ++r) {
            Z[(long)(row0 + lk * 4 + r) * 32 + lm]      = acc0[r];
            Z[(long)(row0 + lk * 4 + r) * 32 + 16 + lm] = acc1[r];
        }
    }
}

// ------------------------------ kernel 2: scan -----------------------------
__device__ __forceinline__ float fast_sigmoid(float x) {
    return __builtin_amdgcn_rcpf(1.0f + __builtin_amdgcn_exp2f(-1.442695041f * x));
}
__device__ __forceinline__ float fast_tanh(float x) {
    return 1.0f - 2.0f * __builtin_amdgcn_rcpf(__builtin_amdgcn_exp2f(2.885390082f * x) + 1.0f);
}

// DPP helpers (16-lane row ops; each row = one batch, qubits replicated x2).
// VERIFIED convention (R1..R4): row_shr:d -> dst[i] = src[i-d] (invalid -> old);
// row_ror:s -> dst[i] = src[(i-s) mod 16].
#define DPP_ROR(V, S) \
    __int_as_float(__builtin_amdgcn_update_dpp(__float_as_int(V), __float_as_int(V), 0x120 | (S), 0xF, 0xF, false))
#define DPP_SHR_ONE(V, D) \
    __int_as_float(__builtin_amdgcn_update_dpp(one_i, __float_as_int(V), 0x110 | (D), 0xF, 0xF, false))
// replicate low half -> high half: row_shr:8, old=V keeps lanes 0-7 intact
#define DPP_REPL8(V) \
    __int_as_float(__builtin_amdgcn_update_dpp(__float_as_int(V), __float_as_int(V), 0x118, 0xF, 0xF, false))

#define PFX3(A) { A *= DPP_SHR_ONE(A, 1); A *= DPP_SHR_ONE(A, 2); A *= DPP_SHR_ONE(A, 4); }

#define PF 8   // prefetch ring depth

// grid: 128 blocks x 64 threads = 8192 = 512 batches * 16 lanes
__global__ __launch_bounds__(64, 1) void qlstm_scan(
    const float* __restrict__ Z,
    const float* __restrict__ Wf, const float* __restrict__ Wi,
    const float* __restrict__ Wu, const float* __restrict__ Wo,
    const float* __restrict__ pf, const float* __restrict__ pi_,
    const float* __restrict__ pu, const float* __restrict__ po,
    float* __restrict__ out)
{
    const int tid = blockIdx.x * 64 + threadIdx.x;   // 0..8191
    const int q   = threadIdx.x & 15;                // lane-in-batch 0..15
    const int kq  = q & 7;                           // qubit index
    const int b   = tid >> 4;                        // batch 0..511
    const int oidx = b * 8 + kq;                     // element index in a slice
    const int woff = kq * DCOMB + DIN;

    // pre-rotated recurrent weights: at rotation s, lane holds hx_{(kq-s)&7}
    f32x2 w01[8], w23[8];
    #pragma unroll
    for (int s = 0; s < 8; ++s) {
        const int j = (kq - s) & 7;
        w01[s] = (f32x2){Wf[woff + j], Wi[woff + j]};
        w23[s] = (f32x2){Wu[woff + j], Wo[woff + j]};
    }
    const float cth0 = __cosf(pf[kq]);
    const float cth1 = __cosf(pi_[kq]);
    const float cth2 = __cosf(pu[kq]);
    const float cth3 = __cosf(po[kq]);
    const int one_i = __float_as_int(1.0f);

    float hx = 0.0f, cx = 0.0f;
    const float4* __restrict__ Zv = (const float4*)Z;
    float* __restrict__ outp = out + oidx;

    float4 ring[PF];
    #pragma unroll
    for (int i = 0; i < PF; ++i) ring[i] = Zv[(i << 12) + oidx];

    for (int t0 = 0; t0 < SEQ; t0 += PF) {
        #pragma unroll
        for (int u = 0; u < PF; ++u) {
            const int t = t0 + u;
            const float4 z = ring[u];
            int tn = t + PF; if (tn > SEQ - 1) tn = SEQ - 1;
            ring[u] = Zv[(tn << 12) + oidx];         // deep prefetch

            // 7 independent DPP rotations of hx (mod-8 exact via replication)
            float h0 = hx;
            float h1 = DPP_ROR(hx, 1), h2 = DPP_ROR(hx, 2);
            float h3 = DPP_ROR(hx, 3), h4 = DPP_ROR(hx, 4);
            float h5 = DPP_ROR(hx, 5), h6 = DPP_ROR(hx, 6);
            float h7 = DPP_ROR(hx, 7);

            // pre = z + hx @ Wh.T : 4 depth-2 pair chains + tree add
            f32x2 s0a = (f32x2){h0, h0} * w01[0] + (f32x2){h1, h1} * w01[1];
            f32x2 s1a = (f32x2){h2, h2} * w01[2] + (f32x2){h3, h3} * w01[3];
            f32x2 s2a = (f32x2){h4, h4} * w01[4] + (f32x2){h5, h5} * w01[5];
            f32x2 s3a = (f32x2){h6, h6} * w01[6] + (f32x2){h7, h7} * w01[7];
            f32x2 s0b = (f32x2){h0, h0} * w23[0] + (f32x2){h1, h1} * w23[1];
            f32x2 s1b = (f32x2){h2, h2} * w23[2] + (f32x2){h3, h3} * w23[3];
            f32x2 s2b = (f32x2){h4, h4} * w23[4] + (f32x2){h5, h5} * w23[5];
            f32x2 s3b = (f32x2){h6, h6} * w23[6] + (f32x2){h7, h7} * w23[7];
            const f32x2 p01 = ((f32x2){z.x, z.y} + (s0a + s1a)) + (s2a + s3a);
            const f32x2 p23 = ((f32x2){z.z, z.w} + (s0b + s1b)) + (s2b + s3b);

            // qgate: a_k = cos(pre_k)*cos(theta_k); gate = cumprod_{j<=k}
            // (lanes 8-15 compute garbage prefixes for kq<4 — discarded)
            float a0 = __cosf(p01.x) * cth0;
            float a1 = __cosf(p01.y) * cth1;
            float a2 = __cosf(p23.x) * cth2;
            float a3 = __cosf(p23.y) * cth3;
            PFX3(a0) PFX3(a1) PFX3(a2) PFX3(a3)

            const float fg = fast_sigmoid(a0);
            const float ig = fast_sigmoid(a1);
            const float ug = fast_tanh(a2);
            const float og = fast_sigmoid(a3);

            cx = fmaf(fg, cx, ig * ug);              // cx valid in lanes 0-7 only
            hx = og * fast_tanh(cx);
            hx = DPP_REPL8(hx);                      // lanes 8-15 <- lanes 0-7

            outp[t << 12] = hx;                      // dup lanes write same bits
        }
    }
    if (q < 8) {
        out[NROWS * 8 + oidx]        = hx;           // final hx (512,8)
        out[NROWS * 8 + 4096 + oidx] = cx;           // final cx (512,8)
    }
}

// ---------------------------------------------------------------------------
extern "C" void kernel_launch(void* const* d_in, const int* in_sizes, int n_in,
                              void* d_out, int out_size, void* d_ws, size_t ws_size,
                              hipStream_t stream) {
    const float* X   = (const float*)d_in[0];
    const float* Wf  = (const float*)d_in[1];
    const float* bfv = (const float*)d_in[2];
    const float* Wi  = (const float*)d_in[3];
    const float* biv = (const float*)d_in[4];
    const float* Wu  = (const float*)d_in[5];
    const float* buv = (const float*)d_in[6];
    const float* Wo  = (const float*)d_in[7];
    const float* bov = (const float*)d_in[8];
    const float* pf  = (const float*)d_in[9];
    const float* pi_ = (const float*)d_in[10];
    const float* pu  = (const float*)d_in[11];
    const float* po  = (const float*)d_in[12];
    float* out = (float*)d_out;
    float* Z   = (float*)d_ws;   // 131072 * 32 * 4 B = 16.8 MB scratch

    qlstm_gemm<<<NROWS / (64 * MCHUNKS), 256, 0, stream>>>(
        X, Wf, Wi, Wu, Wo, bfv, biv, buv, bov, Z);
    qlstm_scan<<<128, 64, 0, stream>>>(Z, Wf, Wi, Wu, Wo, pf, pi_, pu, po, out);
}

// Round 6
// 264.798 us; speedup vs baseline: 1.5724x; 1.0678x over previous
//
#include <hip/hip_runtime.h>
#include <hip/hip_bf16.h>

// ---------------------------------------------------------------------------
// QLSTM: seq=256, batch=512, input=256, H=n_qubits=8.
// Kernel 1 (MFMA, persistent — UNCHANGED from R5/passing): Z[row][kq*4+g].
// Kernel 2 (scan): 16 lanes/batch; low 8 lanes compute gates (f,i), high 8
//   compute (u,o) — half the instructions; recombine via DPP half-swaps.
//   Polynomial activations (bounded inputs) — transcendentals 14 -> 3/step.
// ---------------------------------------------------------------------------

#define SEQ   256
#define BATCH 512
#define DIN   256
#define NROWS (SEQ * BATCH)      // 131072
#define DCOMB 264                // 256 + 8
#define MCHUNKS 4                // 64-row chunks per block (512 blocks)

typedef __attribute__((ext_vector_type(8))) short short8;
typedef __attribute__((ext_vector_type(4))) float f32x4;
typedef __attribute__((ext_vector_type(2))) float f32x2;

__device__ __forceinline__ short f2bf(float f) {
    union { __hip_bfloat16 h; short s; } u;
    u.h = __float2bfloat16(f);
    return u.s;
}
__device__ __forceinline__ float bf2f(short s) {
    union { short s; __hip_bfloat16 h; } u;
    u.s = s;
    return __bfloat162float(u.h);
}

// ------------------------------ kernel 1: gemm -----------------------------
__device__ __forceinline__ short8 pack8(float4 a, float4 b) {
    union { short8 s8; int i[4]; } u;
    union { __hip_bfloat162 h; int i; } v;
    v.h = __float22bfloat162_rn(make_float2(a.x, a.y)); u.i[0] = v.i;
    v.h = __float22bfloat162_rn(make_float2(a.z, a.w)); u.i[1] = v.i;
    v.h = __float22bfloat162_rn(make_float2(b.x, b.y)); u.i[2] = v.i;
    v.h = __float22bfloat162_rn(make_float2(b.z, b.w)); u.i[3] = v.i;
    return u.s8;
}

// Verified layouts (R1..R5 passing): A[m=lane&15][k=(lane>>4)*8+j],
// B[n=lane&15][k=(lane>>4)*8+j], D col=lane&15, row=(lane>>4)*4+reg.
__global__ __launch_bounds__(256) void qlstm_gemm(
    const float* __restrict__ X,
    const float* __restrict__ Wf, const float* __restrict__ Wi,
    const float* __restrict__ Wu, const float* __restrict__ Wo,
    const float* __restrict__ bfv, const float* __restrict__ biv,
    const float* __restrict__ buv, const float* __restrict__ bov,
    float* __restrict__ Z)
{
    const int l   = threadIdx.x & 63;
    const int wid = threadIdx.x >> 6;
    const int lm  = l & 15;
    const int lk  = l >> 4;

    const float* Wg[4] = {Wf, Wi, Wu, Wo};
    const float* Bg[4] = {bfv, biv, buv, bov};

    short8 Bhi[2][8], Blo[2][8];
    float bias[2];
    #pragma unroll
    for (int nt = 0; nt < 2; ++nt) {
        const int c = nt * 16 + lm;                  // col = kq*4 + g
        const float* wrow = Wg[c & 3] + (c >> 2) * DCOMB;
        bias[nt] = Bg[c & 3][c >> 2];
        #pragma unroll
        for (int ks = 0; ks < 8; ++ks) {
            const float* p = wrow + ks * 32 + lk * 8;
            const float4 w0 = *(const float4*)p;
            const float4 w1 = *(const float4*)(p + 4);
            const float wv[8] = {w0.x, w0.y, w0.z, w0.w, w1.x, w1.y, w1.z, w1.w};
            #pragma unroll
            for (int j = 0; j < 8; ++j) {
                const short hi = f2bf(wv[j]);
                Bhi[nt][ks][j] = hi;
                Blo[nt][ks][j] = f2bf(wv[j] - bf2f(hi));
            }
        }
    }

    #pragma unroll
    for (int ch = 0; ch < MCHUNKS; ++ch) {
        const int row0 = (blockIdx.x * MCHUNKS + ch) * 64 + wid * 16;
        const float* xbase = X + (long)(row0 + lm) * DIN + lk * 8;

        float4 xv[16];
        #pragma unroll
        for (int i = 0; i < 16; ++i)
            xv[i] = *(const float4*)(xbase + (i >> 1) * 32 + (i & 1) * 4);

        f32x4 acc0 = (f32x4){bias[0], bias[0], bias[0], bias[0]};
        f32x4 acc1 = (f32x4){bias[1], bias[1], bias[1], bias[1]};
        #pragma unroll
        for (int ks = 0; ks < 8; ++ks) {
            const short8 a = pack8(xv[2 * ks], xv[2 * ks + 1]);
            acc0 = __builtin_amdgcn_mfma_f32_16x16x32_bf16(a, Bhi[0][ks], acc0, 0, 0, 0);
            acc0 = __builtin_amdgcn_mfma_f32_16x16x32_bf16(a, Blo[0][ks], acc0, 0, 0, 0);
            acc1 = __builtin_amdgcn_mfma_f32_16x16x32_bf16(a, Bhi[1][ks], acc1, 0, 0, 0);
            acc1 = __builtin_amdgcn_mfma_f32_16x16x32_bf16(a, Blo[1][ks], acc1, 0, 0, 0);
        }

        #pragma unroll
        for (int r = 0; r < 4; ++r) {
            Z[(long)(row0 + lk * 4 + r) * 32 + lm]      = acc0[r];
            Z[(long)(row0 + lk * 4 + r) * 32 + 16 + lm] = acc1[r];
        }
    }
}

// ------------------------------ kernel 2: scan -----------------------------
// DPP conventions (verified R1..R5 passing):
//   row_shr:d  -> dst[i] = src[i-d], invalid src -> old      (0x110|d)
//   row_ror:s  -> dst[i] = src[(i-s) mod 16]                 (0x120|s)
//   ror:8 therefore swaps 8-lane halves exactly (self-inverse).
//   repl8: row_shr:8 with old=V -> high lanes <- low, low lanes keep V.
#define DPP_ROR(V, S) \
    __int_as_float(__builtin_amdgcn_update_dpp(__float_as_int(V), __float_as_int(V), 0x120 | (S), 0xF, 0xF, false))
#define SWAP8(V) \
    __int_as_float(__builtin_amdgcn_update_dpp(__float_as_int(V), __float_as_int(V), 0x128, 0xF, 0xF, false))
#define DPP_REPL8(V) \
    __int_as_float(__builtin_amdgcn_update_dpp(__float_as_int(V), __float_as_int(V), 0x118, 0xF, 0xF, false))

// prefix-product stage on an f32x2 pair, mod-8 groups inside the 16-lane row:
// R1-verified kq>=d select handles the lane-8 group boundary.
#define PSTG(A, D, PM) { \
    float s0_ = __int_as_float(__builtin_amdgcn_update_dpp(one_i, __float_as_int(A.x), 0x110 | (D), 0xF, 0xF, false)); \
    float s1_ = __int_as_float(__builtin_amdgcn_update_dpp(one_i, __float_as_int(A.y), 0x110 | (D), 0xF, 0xF, false)); \
    A *= (f32x2){ (PM) ? s0_ : 1.0f, (PM) ? s1_ : 1.0f }; }

#define PF 8   // prefetch ring depth

// grid: 128 blocks x 64 threads = 8192 = 512 batches * 16 lanes
__global__ __launch_bounds__(64, 1) void qlstm_scan(
    const float* __restrict__ Z,
    const float* __restrict__ Wf, const float* __restrict__ Wi,
    const float* __restrict__ Wu, const float* __restrict__ Wo,
    const float* __restrict__ pf, const float* __restrict__ pi_,
    const float* __restrict__ pu, const float* __restrict__ po,
    float* __restrict__ out)
{
    const int tx  = threadIdx.x;
    const int q   = tx & 15;                         // lane-in-batch 0..15
    const int kq  = q & 7;                           // qubit index
    const int hi  = q >> 3;                          // 0: gates (f,i); 1: (u,o)
    const int b   = (blockIdx.x * 64 + tx) >> 4;     // batch 0..511
    const int oidx = b * 8 + kq;
    const int woff = kq * DCOMB + DIN;

    // per-lane gate-pair selection
    const float* WgA = hi ? Wu : Wf;
    const float* WgB = hi ? Wo : Wi;
    f32x2 wp[8];                                     // rotated recurrent weights
    #pragma unroll
    for (int s = 0; s < 8; ++s) {
        const int j = (kq - s) & 7;
        wp[s] = (f32x2){WgA[woff + j], WgB[woff + j]};
    }
    const f32x2 cth = (f32x2){__cosf((hi ? pu : pf)[kq]),
                              __cosf((hi ? po : pi_)[kq])};

    // activation poly: act(x) = k0 + x*(k1 + t*(k2 + t*(k3 + t*k4))), t=x^2
    // comp0: sigmoid (low) / tanh minimax (high); comp1: sigmoid. |x|<=1.
    const float SK1 = 0.25f, SK2 = -0.0208333333f, SK3 = 0.0020833333f,
                SK4 = -0.00021082f;
    const f32x2 k0 = (f32x2){hi ? 0.0f : 0.5f, 0.5f};
    const f32x2 k1 = (f32x2){hi ? 0.9999016f : SK1, SK1};
    const f32x2 k2 = (f32x2){hi ? -0.3310485f : SK2, SK2};
    const f32x2 k3 = (f32x2){hi ? 0.1204423f : SK3, SK3};
    const f32x2 k4 = (f32x2){hi ? -0.0277012f : SK4, SK4};

    const bool pm1 = kq >= 1, pm2 = kq >= 2, pm4 = kq >= 4;
    const int one_i = __float_as_int(1.0f);

    float hx = 0.0f, cx = 0.0f;
    // per-lane float2 of Z: gates (2*hi, 2*hi+1) of qubit kq
    const float2* __restrict__ Zv2 = (const float2*)Z;
    const int zoff = b * 16 + kq * 2 + hi;           // float2 index in a t-slice
    float* __restrict__ outp = out + oidx;

    float2 ring[PF];
    #pragma unroll
    for (int i = 0; i < PF; ++i) ring[i] = Zv2[(i << 13) + zoff];

    for (int t0 = 0; t0 < SEQ; t0 += PF) {
        #pragma unroll
        for (int u = 0; u < PF; ++u) {
            const int t = t0 + u;
            const float2 z2 = ring[u];
            int tn = t + PF; if (tn > SEQ - 1) tn = SEQ - 1;
            ring[u] = Zv2[(tn << 13) + zoff];        // deep prefetch

            // hx rotations (hx replicated mod 8 across the 16-lane row)
            const float h0 = hx;
            const float h1 = DPP_ROR(hx, 1), h2 = DPP_ROR(hx, 2);
            const float h3 = DPP_ROR(hx, 3), h4 = DPP_ROR(hx, 4);
            const float h5 = DPP_ROR(hx, 5), h6 = DPP_ROR(hx, 6);
            const float h7 = DPP_ROR(hx, 7);

            // pre-pair = z + hx @ Wh.T (this lane's 2 gates only)
            f32x2 ca = (f32x2){h0, h0} * wp[0] + (f32x2){h1, h1} * wp[1];
            f32x2 cb = (f32x2){h4, h4} * wp[4] + (f32x2){h5, h5} * wp[5];
            ca += (f32x2){h2, h2} * wp[2];
            cb += (f32x2){h6, h6} * wp[6];
            ca += (f32x2){h3, h3} * wp[3];
            cb += (f32x2){h7, h7} * wp[7];
            const f32x2 p = ((f32x2){z2.x, z2.y} + ca) + cb;

            // qgate: a = cos(pre)*cos(theta), then mod-8 prefix product
            f32x2 A = (f32x2){__cosf(p.x), __cosf(p.y)} * cth;
            PSTG(A, 1, pm1) PSTG(A, 2, pm2) PSTG(A, 4, pm4)

            // activations via per-lane poly (|A|<=1)
            const f32x2 t2 = A * A;
            f32x2 r = k3 + t2 * k4;
            r = k2 + t2 * r;
            r = k1 + t2 * r;
            const f32x2 P = k0 + A * r;
            const float v1 = P.x;                    // low: fg   high: ug
            const float v2 = P.y;                    // low: ig   high: og

            // cx = fg*cx + ig*ug   (valid in low lanes)
            const float swu = SWAP8(v1);             // low lanes receive ug
            cx = fmaf(v1, cx, v2 * swu);

            // tanh(cx) via Pade[5/4] (|cx| <= ~2.1), 1 rcp
            const float tq  = cx * cx;
            const float num = cx * fmaf(tq, fmaf(tq, 1.0f, 105.0f), 945.0f);
            const float den = fmaf(tq, fmaf(tq, 15.0f, 420.0f), 945.0f);
            const float tc  = num * __builtin_amdgcn_rcpf(den);

            // hx = og * tanh(cx): og lives high, tc lives low
            const float stc = SWAP8(tc);             // high lanes receive tc
            const float hh  = v2 * stc;              // valid in high lanes
            hx = SWAP8(hh);                          // valid in low lanes
            hx = DPP_REPL8(hx);                      // replicate low -> high

            outp[t << 12] = hx;                      // dup lanes write same bits
        }
    }
    if (q < 8) {
        out[NROWS * 8 + oidx]        = hx;           // final hx (512,8)
        out[NROWS * 8 + 4096 + oidx] = cx;           // final cx (512,8)
    }
}

// ---------------------------------------------------------------------------
extern "C" void kernel_launch(void* const* d_in, const int* in_sizes, int n_in,
                              void* d_out, int out_size, void* d_ws, size_t ws_size,
                              hipStream_t stream) {
    const float* X   = (const float*)d_in[0];
    const float* Wf  = (const float*)d_in[1];
    const float* bfv = (const float*)d_in[2];
    const float* Wi  = (const float*)d_in[3];
    const float* biv = (const float*)d_in[4];
    const float* Wu  = (const float*)d_in[5];
    const float* buv = (const float*)d_in[6];
    const float* Wo  = (const float*)d_in[7];
    const float* bov = (const float*)d_in[8];
    const float* pf  = (const float*)d_in[9];
    const float* pi_ = (const float*)d_in[10];
    const float* pu  = (const float*)d_in[11];
    const float* po  = (const float*)d_in[12];
    float* out = (float*)d_out;
    float* Z   = (float*)d_ws;   // 131072 * 32 * 4 B = 16.8 MB scratch

    qlstm_gemm<<<NROWS / (64 * MCHUNKS), 256, 0, stream>>>(
        X, Wf, Wi, Wu, Wo, bfv, biv, buv, bov, Z);
    qlstm_scan<<<128, 64, 0, stream>>>(Z, Wf, Wi, Wu, Wo, pf, pi_, pu, po, out);
}